// Round 3
// baseline (309.773 us; speedup 1.0000x reference)
//
#include <hip/hip_runtime.h>
#include <cstdint>
#include <cstddef>

// Problem constants
#define B_   4
#define S_   4096
#define H_   1024
#define NH_  16
#define D_   64
#define M_TOT (B_ * S_)    // 16384 rows of hidden
#define K_TOT H_           // 1024 reduction dim
#define N_TOT (3 * H_)     // 3072 = concat(Q,K,V) output cols
#define SCALE_ 0.125f      // 1/sqrt(64)
#define NCH 16             // chunks for global-attention online softmax
#define CH (S_ / NCH)      // 256 positions per chunk

typedef __bf16 bf16x8 __attribute__((ext_vector_type(8)));
typedef float  f32x4  __attribute__((ext_vector_type(4)));

__device__ __forceinline__ unsigned short f2b(float x) {
    unsigned int u = __float_as_uint(x);
    u += 0x7FFFu + ((u >> 16) & 1u);          // round-to-nearest-even
    return (unsigned short)(u >> 16);
}
__device__ __forceinline__ float b2f(unsigned int u) {   // u = bf16 bits in low 16
    return __uint_as_float(u << 16);
}
__device__ __forceinline__ void unp8(uint4 u, float* f) {
    f[0] = b2f(u.x & 0xffffu); f[1] = b2f(u.x >> 16);
    f[2] = b2f(u.y & 0xffffu); f[3] = b2f(u.y >> 16);
    f[4] = b2f(u.z & 0xffffu); f[5] = b2f(u.z >> 16);
    f[6] = b2f(u.w & 0xffffu); f[7] = b2f(u.w >> 16);
}
__device__ __forceinline__ unsigned int pack2(float lo, float hi) {
    return (unsigned int)f2b(lo) | ((unsigned int)f2b(hi) << 16);
}

// ------------------------------------------------- fused fp32->bf16 converts
__global__ __launch_bounds__(256) void cvt_all(const float* __restrict__ hs,
                                               const float* __restrict__ wq,
                                               const float* __restrict__ wk,
                                               const float* __restrict__ wv,
                                               unsigned short* __restrict__ Xb,
                                               unsigned short* __restrict__ Wb) {
    const int i = blockIdx.x * 256 + threadIdx.x;
    const int X8 = M_TOT * K_TOT / 8;          // 2097152 = 2^21
    const float4* sp;
    uint4* dp;
    int off;
    if (i < X8) {
        sp = (const float4*)hs;
        dp = (uint4*)Xb;
        off = i;
    } else {
        const int j = i - X8;
        const int w = j >> 17;                 // H*H/8 = 2^17
        off = j & 0x1ffff;
        sp = (const float4*)((w == 0) ? wq : (w == 1 ? wk : wv));
        dp = (uint4*)(Wb + (size_t)w * H_ * H_);
    }
    const float4 v0 = sp[off * 2];
    const float4 v1 = sp[off * 2 + 1];
    uint4 o;
    o.x = pack2(v0.x, v0.y);
    o.y = pack2(v0.z, v0.w);
    o.z = pack2(v1.x, v1.y);
    o.w = pack2(v1.z, v1.w);
    dp[off] = o;
}

// ---------------------------------------------------------------- QKV GEMM
// C[m,n] = sum_k A[m,k]*W[n,k] (+bias[n]) ; A: M x K bf16, W: N x K bf16, C: M x N bf16
//
// Round 6: R2's fine-phase schedule with the measured poison removed:
//  * ZERO sched_barrier(0) in the loop body (m141: order-pinning cost −42% there;
//    R2 post-mortem attributes the 150->163 regression to the 6 pins/slice).
//  * 4 barriers/slice (template ratio): vmcnt(8) folded before phase-1's closing
//    barrier instead of a 5th barrier pair.
//  * zero-conflict swizzle kept (R2 measured SQ_LDS_BANK_CONFLICT = 0).
//  * 4-deep ring, counted vmcnt(8), prefetch distance 3 — proven race-free in R1/R2.
//
// Phase structure per K=32 slice s (template form, no compiler pins):
//  P0: 8 ds_reads (A mi0-3, B ni0-3) ; STAGE_A(s+3) ; BAR ; lgkm(0) ; prio1 ;
//      16 MFMA (mi0-3 x ni0-3) ; prio0 ; BAR
//  P1: 4 ds_reads (A mi4-7) ; STAGE_B(s+3) ; BAR ; lgkm(0) ; prio1 ;
//      16 MFMA (mi4-7 x ni0-3) ; prio0 ; vmcnt(8) ; BAR
// vmcnt(8) retires slice s+1's 4 loads (s+2,s+3 = 8 newest stay in flight).
__global__ __launch_bounds__(512) void gemm_qkv(const unsigned short* __restrict__ A,
                                                const unsigned short* __restrict__ W,
                                                const float* __restrict__ bq,
                                                const float* __restrict__ bk,
                                                const float* __restrict__ bv,
                                                unsigned short* __restrict__ C) {
    __shared__ unsigned short Asl[4][256 * 32] __attribute__((aligned(16)));
    __shared__ unsigned short Bsl[4][256 * 32] __attribute__((aligned(16)));

    const int tid  = threadIdx.x;
    const int wid  = tid >> 6;
    const int lane = tid & 63;
    const int wm = wid >> 2, wn = wid & 3;     // 2 x 4 wave grid

    // XCD-aware bijective swizzle: 768 blocks = 8 XCDs x 96
    const int wg = (blockIdx.x & 7) * 96 + (blockIdx.x >> 3);
    const int bx = wg % 12;                    // N tile (3072/256)
    const int by = wg / 12;                    // M tile (16384/256)
    const int m0 = by * 256;
    const int n0 = bx * 256;

    // staging addressing: thread tid covers LDS bytes [tid*16,+16) of an 8KB issue
    // row = tid>>2 (64B rows, 4 slots), slot = tid&3; global chunk = slot ^ ((row>>1)&3)
    const int sr  = tid >> 2;                          // 0..127
    const int sch = (tid & 3) ^ ((sr >> 1) & 3);       // zero-conflict swizzle (R2-verified)
    const size_t aBase = (size_t)(m0 + sr) * K_TOT + sch * 8;
    const size_t bBase = (size_t)(n0 + sr) * K_TOT + sch * 8;
    const int ldsBase = wid * 512;                     // wave-uniform 1KB chunk (ushort idx)

    // fragment-read: lane wants chunk lane>>4 of row (16-aligned base + rl);
    // (row>>1)&3 == (rl>>1)&3, so slot = (lane>>4) ^ ((rl>>1)&3)
    const int rl = lane & 15;
    const int sslot = ((lane >> 4) ^ ((rl >> 1) & 3)) * 8;

    f32x4 acc[8][4];
#pragma unroll
    for (int i = 0; i < 8; i++)
#pragma unroll
        for (int j = 0; j < 4; j++) acc[i][j] = (f32x4){0.f, 0.f, 0.f, 0.f};

    auto STAGE_A = [&](int s) {   // 2 x global_load_lds: A rows 0-127, 128-255
        const int bsel = s & 3;
        const unsigned short* ga = A + aBase + (size_t)s * 32;
        __builtin_amdgcn_global_load_lds(
            (const __attribute__((address_space(1))) void*)ga,
            (__attribute__((address_space(3))) void*)&Asl[bsel][ldsBase], 16, 0, 0);
        __builtin_amdgcn_global_load_lds(
            (const __attribute__((address_space(1))) void*)(ga + 128 * K_TOT),
            (__attribute__((address_space(3))) void*)&Asl[bsel][128 * 32 + ldsBase], 16, 0, 0);
    };
    auto STAGE_B = [&](int s) {   // 2 x global_load_lds: B rows 0-127, 128-255
        const int bsel = s & 3;
        const unsigned short* gb = W + bBase + (size_t)s * 32;
        __builtin_amdgcn_global_load_lds(
            (const __attribute__((address_space(1))) void*)gb,
            (__attribute__((address_space(3))) void*)&Bsl[bsel][ldsBase], 16, 0, 0);
        __builtin_amdgcn_global_load_lds(
            (const __attribute__((address_space(1))) void*)(gb + 128 * K_TOT),
            (__attribute__((address_space(3))) void*)&Bsl[bsel][128 * 32 + ldsBase], 16, 0, 0);
    };

    // one K=32 slice as two fine phases; NO sched_barrier pins (m141 lesson).
    // vm: 8 in main loop, 4/0 in epilogue drain; <0 means skip (stage-less slices
    // before a drain already counted).
    auto PHASES = [&](int s, bool doStage, int vm) {
        const int bsel = s & 3;
        const unsigned short* As = Asl[bsel];
        const unsigned short* Bs = Bsl[bsel];
        bf16x8 af0[4], af1[4], bfv[4];
        // ---------- phase 0
#pragma unroll
        for (int mi = 0; mi < 4; mi++)
            af0[mi] = *(const bf16x8*)&As[(wm * 128 + mi * 16 + rl) * 32 + sslot];
#pragma unroll
        for (int ni = 0; ni < 4; ni++)
            bfv[ni] = *(const bf16x8*)&Bs[(wn * 64 + ni * 16 + rl) * 32 + sslot];
        if (doStage) STAGE_A(s + 3);
        __builtin_amdgcn_s_barrier();
        asm volatile("s_waitcnt lgkmcnt(0)" ::: "memory");
        __builtin_amdgcn_s_setprio(1);
#pragma unroll
        for (int mi = 0; mi < 4; mi++)
#pragma unroll
            for (int ni = 0; ni < 4; ni++)
                acc[mi][ni] = __builtin_amdgcn_mfma_f32_16x16x32_bf16(af0[mi], bfv[ni], acc[mi][ni], 0, 0, 0);
        __builtin_amdgcn_s_setprio(0);
        __builtin_amdgcn_s_barrier();
        // ---------- phase 1
#pragma unroll
        for (int mi = 0; mi < 4; mi++)
            af1[mi] = *(const bf16x8*)&As[(wm * 128 + (mi + 4) * 16 + rl) * 32 + sslot];
        if (doStage) STAGE_B(s + 3);
        __builtin_amdgcn_s_barrier();
        asm volatile("s_waitcnt lgkmcnt(0)" ::: "memory");
        __builtin_amdgcn_s_setprio(1);
#pragma unroll
        for (int mi = 0; mi < 4; mi++)
#pragma unroll
            for (int ni = 0; ni < 4; ni++)
                acc[mi + 4][ni] = __builtin_amdgcn_mfma_f32_16x16x32_bf16(af1[mi], bfv[ni], acc[mi + 4][ni], 0, 0, 0);
        __builtin_amdgcn_s_setprio(0);
        if (vm == 8)      asm volatile("s_waitcnt vmcnt(8)" ::: "memory");
        else if (vm == 4) asm volatile("s_waitcnt vmcnt(4)" ::: "memory");
        else if (vm == 0) asm volatile("s_waitcnt vmcnt(0)" ::: "memory");
        __builtin_amdgcn_s_barrier();
    };

    // prologue: 3 slices in flight, wait oldest (slice 0), publish
    STAGE_A(0); STAGE_B(0); STAGE_A(1); STAGE_B(1); STAGE_A(2); STAGE_B(2);
    asm volatile("s_waitcnt vmcnt(8)" ::: "memory");
    __builtin_amdgcn_s_barrier();

    // main loop: 32 K-slices; steady state 12 loads in flight, vmcnt(8) retires
    // exactly slice s+1's 4. NEVER vmcnt(0) in the loop.
#pragma unroll 1
    for (int s = 0; s < 29; ++s) PHASES(s, true, 8);
    // epilogue drain: 8 -> 4 -> 0 outstanding
    PHASES(29, false, 4);
    PHASES(30, false, 0);
    PHASES(31, false, -1);

    // C write + bias (verified fragment->(row,col) convention)
    const int col_l = lane & 15;
    const int quad  = lane >> 4;
#pragma unroll
    for (int mi = 0; mi < 8; mi++) {
#pragma unroll
        for (int ni = 0; ni < 4; ni++) {
            const int gc = n0 + wn * 64 + ni * 16 + col_l;
            const float bias = (gc < H_) ? bq[gc] : (gc < 2 * H_ ? bk[gc - H_] : bv[gc - 2 * H_]);
#pragma unroll
            for (int i = 0; i < 4; i++) {
                const int gr = m0 + wm * 128 + mi * 16 + quad * 4 + i;
                C[(size_t)gr * N_TOT + gc] = f2b(acc[mi][ni][i] + bias);
            }
        }
    }
}

// ------------------------------------------------- global attention (s=0 query)
// grid (B*NH, NCH=16), 256 thr. Phase 1: one key per thread (uint4 K loads).
// Phase 2 (round 6): vectorized PV — lane = (s-group g, d-octet l); 8 iters of
// uint4 V loads (16B/lane, was 64 scalar 2B loads = Common-mistake #2), then
// 3x shfl_xor reduce across the 8 s-groups.
__global__ __launch_bounds__(256) void gattn_part(const unsigned short* __restrict__ QKV,
                                                  const float* __restrict__ mask,
                                                  float* __restrict__ Pm,
                                                  float* __restrict__ Pl,
                                                  float* __restrict__ Po) {
    const int bh = blockIdx.x;
    const int b = bh >> 4, h = bh & 15;
    const int chunk = blockIdx.y;
    const int tid = threadIdx.x;
    const int w = tid >> 6, lane = tid & 63;

    __shared__ float gq_sh[D_];
    __shared__ float pr[CH];
    __shared__ float red[8];
    __shared__ float osum[4][D_];

    const unsigned short* gqp = QKV + (size_t)(b * S_) * N_TOT + h * D_;
    if (tid < D_) gq_sh[tid] = b2f(gqp[tid]);
    __syncthreads();

    const int s0 = chunk * CH;
    const int s  = s0 + tid;
    const uint4* kp4 = (const uint4*)(QKV + (size_t)(b * S_ + s) * N_TOT + H_ + h * D_);
    float acc = 0.f;
#pragma unroll
    for (int c = 0; c < 8; c++) {
        uint4 r = kp4[c];
        acc += b2f(r.x & 0xffffu) * gq_sh[c * 8 + 0];
        acc += b2f(r.x >> 16)     * gq_sh[c * 8 + 1];
        acc += b2f(r.y & 0xffffu) * gq_sh[c * 8 + 2];
        acc += b2f(r.y >> 16)     * gq_sh[c * 8 + 3];
        acc += b2f(r.z & 0xffffu) * gq_sh[c * 8 + 4];
        acc += b2f(r.z >> 16)     * gq_sh[c * 8 + 5];
        acc += b2f(r.w & 0xffffu) * gq_sh[c * 8 + 6];
        acc += b2f(r.w >> 16)     * gq_sh[c * 8 + 7];
    }
    const float sv = acc * SCALE_ + mask[b * S_ + s];

    float wmax = sv;
#pragma unroll
    for (int m = 32; m >= 1; m >>= 1) wmax = fmaxf(wmax, __shfl_xor(wmax, m, 64));
    if (lane == 0) red[w] = wmax;
    __syncthreads();
    const float bmax = fmaxf(fmaxf(red[0], red[1]), fmaxf(red[2], red[3]));

    const float p = __expf(sv - bmax);
    pr[tid] = p;
    float wsum = p;
#pragma unroll
    for (int m = 32; m >= 1; m >>= 1) wsum += __shfl_xor(wsum, m, 64);
    if (lane == 0) red[4 + w] = wsum;
    __syncthreads();   // publishes pr[] for phase 2
    const float bsum = red[4] + red[5] + red[6] + red[7];

    // o[d] = sum_s p[s] * v[s][d]; wave w covers 64 consecutive s.
    // lane = g*8 + l: g = s-subgroup (8 s per wave-iter), l = d-octet.
    const int g = lane >> 3;
    const int l = lane & 7;
    float o8[8];
#pragma unroll
    for (int j = 0; j < 8; j++) o8[j] = 0.f;
    const int sbase = s0 + w * 64;
#pragma unroll
    for (int i = 0; i < 8; i++) {
        const int si = sbase + i * 8 + g;
        const uint4 vu = *(const uint4*)(QKV + (size_t)(b * S_ + si) * N_TOT + 2 * H_ + h * D_ + l * 8);
        float vf[8];
        unp8(vu, vf);
        const float pw = pr[w * 64 + i * 8 + g];
#pragma unroll
        for (int j = 0; j < 8; j++) o8[j] += pw * vf[j];
    }
    // reduce across the 8 s-groups (lanes l, l+8, ..., l+56)
#pragma unroll
    for (int j = 0; j < 8; j++) {
        o8[j] += __shfl_xor(o8[j], 8, 64);
        o8[j] += __shfl_xor(o8[j], 16, 64);
        o8[j] += __shfl_xor(o8[j], 32, 64);
    }
    if (g == 0) {
#pragma unroll
        for (int j = 0; j < 8; j++) osum[w][l * 8 + j] = o8[j];
    }
    __syncthreads();
    if (tid < D_) {
        const float ot = osum[0][tid] + osum[1][tid] + osum[2][tid] + osum[3][tid];
        Po[(size_t)(bh * NCH + chunk) * D_ + tid] = ot;
        if (tid == 0) {
            Pm[bh * NCH + chunk] = bmax;
            Pl[bh * NCH + chunk] = bsum;
        }
    }
}

// ------------------------------------------------- local attention + combine
__global__ __launch_bounds__(256) void lattn(const unsigned short* __restrict__ QKV,
                                             float* __restrict__ ctx,
                                             float* __restrict__ lat,
                                             const float* __restrict__ Pm,
                                             const float* __restrict__ Pl,
                                             const float* __restrict__ Po) {
    const int bh = blockIdx.x;
    const int b = bh >> 4, h = bh & 15;

    if (blockIdx.y == 128) {
        const int d = threadIdx.x;
        if (d < D_) {
            float ms = -1e30f;
#pragma unroll
            for (int c = 0; c < NCH; c++) ms = fmaxf(ms, Pm[bh * NCH + c]);
            float z = 0.f, o = 0.f;
#pragma unroll
            for (int c = 0; c < NCH; c++) {
                const float e = __expf(Pm[bh * NCH + c] - ms);
                z += Pl[bh * NCH + c] * e;
                o += Po[(size_t)(bh * NCH + c) * D_ + d] * e;
            }
            ctx[(size_t)b * S_ * H_ + (size_t)h * D_ + d] = o / z;
        }
        return;
    }

    const int w = threadIdx.x >> 6, lane = threadIdx.x & 63;
    const int g = lane >> 3;     // s-subgroup within wave
    const int l = lane & 7;      // d-octet index
    const int s = 1 + blockIdx.y * 32 + w * 8 + g;
    if (s >= S_) return;         // only the very last 8-lane group; no later barriers

    const size_t rowS = (size_t)(b * S_ + s) * N_TOT + h * D_ + l * 8;
    const size_t row0 = (size_t)(b * S_) * N_TOT + h * D_ + l * 8;

    uint4 qu  = *(const uint4*)(QKV + rowS);
    uint4 ku  = *(const uint4*)(QKV + rowS + H_);
    uint4 k0u = *(const uint4*)(QKV + row0 + H_);
    float qf[8], kf[8], k0f[8];
    unp8(qu, qf); unp8(ku, kf); unp8(k0u, k0f);

    float ps = 0.f, pg = 0.f;
#pragma unroll
    for (int i = 0; i < 8; i++) { ps += qf[i] * kf[i]; pg += qf[i] * k0f[i]; }
#pragma unroll
    for (int m = 1; m < 8; m <<= 1) {   // reduce within the 8-lane d-group
        ps += __shfl_xor(ps, m, 64);
        pg += __shfl_xor(pg, m, 64);
    }
    ps *= SCALE_; pg *= SCALE_;
    const float mx = fmaxf(ps, pg);
    const float e0 = __expf(ps - mx), e1 = __expf(pg - mx);
    const float z = e0 + e1;
    const float p0 = e0 / z, p1 = e1 / z;

    uint4 vu  = *(const uint4*)(QKV + rowS + 2 * H_);
    uint4 v0u = *(const uint4*)(QKV + row0 + 2 * H_);
    float vf[8], v0f[8];
    unp8(vu, vf); unp8(v0u, v0f);

    float* cp = ctx + (size_t)b * (S_ * H_) + (size_t)s * H_ + h * D_ + l * 8;
    float4 o0, o1;
    o0.x = p0 * vf[0] + p1 * v0f[0];
    o0.y = p0 * vf[1] + p1 * v0f[1];
    o0.z = p0 * vf[2] + p1 * v0f[2];
    o0.w = p0 * vf[3] + p1 * v0f[3];
    o1.x = p0 * vf[4] + p1 * v0f[4];
    o1.y = p0 * vf[5] + p1 * v0f[5];
    o1.z = p0 * vf[6] + p1 * v0f[6];
    o1.w = p0 * vf[7] + p1 * v0f[7];
    ((float4*)cp)[0] = o0;
    ((float4*)cp)[1] = o1;

    if (l == 0) {
        float2 lp; lp.x = p0; lp.y = p1;
        ((float2*)(lat + ((size_t)bh * (S_ - 1) + (s - 1)) * 2))[0] = lp;
    }
}

// ---------------------------------------------------------------- launcher
extern "C" void kernel_launch(void* const* d_in, const int* in_sizes, int n_in,
                              void* d_out, int out_size, void* d_ws, size_t ws_size,
                              hipStream_t stream) {
    const float* hs   = (const float*)d_in[0];
    const float* mask = (const float*)d_in[1];
    const float* Wq   = (const float*)d_in[2];
    const float* bq   = (const float*)d_in[3];
    const float* Wk   = (const float*)d_in[4];
    const float* bk   = (const float*)d_in[5];
    const float* Wv   = (const float*)d_in[6];
    const float* bv   = (const float*)d_in[7];

    float* out = (float*)d_out;                       // (B,S,H) fp32
    float* lat = out + (size_t)B_ * S_ * H_;          // (B,NH,S-1,1,2) fp32

    char* ws = (char*)d_ws;
    const size_t offXb  = 0;
    const size_t offWb  = offXb  + (size_t)M_TOT * K_TOT * 2;
    const size_t offQKV = offWb  + (size_t)3 * H_ * H_ * 2;
    const size_t offPm  = offQKV + (size_t)M_TOT * N_TOT * 2;
    const size_t offPl  = offPm  + (size_t)B_ * NH_ * NCH * 4;
    const size_t offPo  = offPl  + (size_t)B_ * NH_ * NCH * 4;

    unsigned short* Xb  = (unsigned short*)(ws + offXb);
    unsigned short* Wb  = (unsigned short*)(ws + offWb);
    unsigned short* QKV = (unsigned short*)(ws + offQKV);
    float* Pm = (float*)(ws + offPm);
    float* Pl = (float*)(ws + offPl);
    float* Po = (float*)(ws + offPo);

    const int total8 = M_TOT * K_TOT / 8 + 3 * H_ * H_ / 8;   // 2490368, /256 exact
    hipLaunchKernelGGL(cvt_all, dim3(total8 / 256), dim3(256), 0, stream,
                       hs, Wq, Wk, Wv, Xb, Wb);
    hipLaunchKernelGGL(gemm_qkv, dim3(12 * 64), dim3(512), 0, stream,
                       Xb, Wb, bq, bk, bv, QKV);
    hipLaunchKernelGGL(gattn_part, dim3(B_ * NH_, NCH), dim3(256), 0, stream, QKV, mask, Pm, Pl, Po);
    hipLaunchKernelGGL(lattn, dim3(B_ * NH_, 129), dim3(256), 0, stream, QKV, out, lat, Pm, Pl, Po);
}

// Round 4
// 286.167 us; speedup vs baseline: 1.0825x; 1.0825x over previous
//
#include <hip/hip_runtime.h>
#include <cstdint>
#include <cstddef>

// Problem constants
#define B_   4
#define S_   4096
#define H_   1024
#define NH_  16
#define D_   64
#define M_TOT (B_ * S_)    // 16384 rows of hidden
#define K_TOT H_           // 1024 reduction dim
#define N_TOT (3 * H_)     // 3072 = concat(Q,K,V) output cols
#define SCALE_ 0.125f      // 1/sqrt(64)
#define NCH 16             // chunks for global-attention online softmax
#define CH (S_ / NCH)      // 256 positions per chunk

typedef __bf16 bf16x8 __attribute__((ext_vector_type(8)));
typedef float  f32x4  __attribute__((ext_vector_type(4)));

__device__ __forceinline__ unsigned short f2b(float x) {
    unsigned int u = __float_as_uint(x);
    u += 0x7FFFu + ((u >> 16) & 1u);          // round-to-nearest-even
    return (unsigned short)(u >> 16);
}
__device__ __forceinline__ float b2f(unsigned int u) {   // u = bf16 bits in low 16
    return __uint_as_float(u << 16);
}
__device__ __forceinline__ void unp8(uint4 u, float* f) {
    f[0] = b2f(u.x & 0xffffu); f[1] = b2f(u.x >> 16);
    f[2] = b2f(u.y & 0xffffu); f[3] = b2f(u.y >> 16);
    f[4] = b2f(u.z & 0xffffu); f[5] = b2f(u.z >> 16);
    f[6] = b2f(u.w & 0xffffu); f[7] = b2f(u.w >> 16);
}
__device__ __forceinline__ unsigned int pack2(float lo, float hi) {
    return (unsigned int)f2b(lo) | ((unsigned int)f2b(hi) << 16);
}

// ------------------------------------------------- fused fp32->bf16 converts
__global__ __launch_bounds__(256) void cvt_all(const float* __restrict__ hs,
                                               const float* __restrict__ wq,
                                               const float* __restrict__ wk,
                                               const float* __restrict__ wv,
                                               unsigned short* __restrict__ Xb,
                                               unsigned short* __restrict__ Wb) {
    const int i = blockIdx.x * 256 + threadIdx.x;
    const int X8 = M_TOT * K_TOT / 8;          // 2097152 = 2^21
    const float4* sp;
    uint4* dp;
    int off;
    if (i < X8) {
        sp = (const float4*)hs;
        dp = (uint4*)Xb;
        off = i;
    } else {
        const int j = i - X8;
        const int w = j >> 17;                 // H*H/8 = 2^17
        off = j & 0x1ffff;
        sp = (const float4*)((w == 0) ? wq : (w == 1 ? wk : wv));
        dp = (uint4*)(Wb + (size_t)w * H_ * H_);
    }
    const float4 v0 = sp[off * 2];
    const float4 v1 = sp[off * 2 + 1];
    uint4 o;
    o.x = pack2(v0.x, v0.y);
    o.y = pack2(v0.z, v0.w);
    o.z = pack2(v1.x, v1.y);
    o.w = pack2(v1.z, v1.w);
    dp[off] = o;
}

// ---------------------------------------------------------------- QKV GEMM
// C[m,n] = sum_k A[m,k]*W[n,k] (+bias[n]) ; A: M x K bf16, W: N x K bf16, C: M x N bf16
//
// Round 7: m201-geometry port. 256x256 tile, BK=64, 8 waves (2Mx4N), per-wave 128x64.
// LDS: 2 buffers x (A 32KB + B 32KB) = 128 KB. 16 K-tiles; 4 phases per tile,
// 16 MFMA each; ds_reads 12/4/8/0; stage slots placed in read-light phases;
// ONE counted vmcnt(6) per tile boundary (template value, re-derived below).
//
// Swizzle (both-sides involution, rule #21): LDS row r slot (H,S) (H = 64B k-half,
// S = 16B chunk) holds global (kk = H ^ ((r>>2)&1), ch = S ^ (r&3)). ds_read_b128
// then touches all 32 banks uniformly (8 word-accesses/bank, 2 lanes/slot = free).
//
// Stage schedule per tile t (steady state), each half = 128 rows = 2 loads:
//   d0: A-half1(t+1)   [overwrites A1(t-1), last read d2(t-1) -> safe]
//   d2: B-half0,B-half1(t+2)  [overwrite B*(t), last read d1(t) -> safe]
//   d3: A-half0(t+2)   [overwrites A0(t), last read d2(t) -> safe]
// vmcnt ledger: 8 loads issued/tile; boundary vmcnt(6) leaves exactly
// {B0,B1,A0}(t+2) in flight and certifies tile t+1 fully landed.
// Reads: d0: A(mi0-3)+B(ni0-1); d1: B(ni2-3); d2: A(mi4-7); d3: none.
// MFMA:  d0: mi0-3 x ni0-1; d1: mi0-3 x ni2-3; d2: mi4-7 x ni2-3; d3: mi4-7 x ni0-1.
__global__ __launch_bounds__(512) void gemm_qkv(const unsigned short* __restrict__ A,
                                                const unsigned short* __restrict__ W,
                                                const float* __restrict__ bq,
                                                const float* __restrict__ bk,
                                                const float* __restrict__ bv,
                                                unsigned short* __restrict__ C) {
    __shared__ unsigned short Asl[2][256 * 64] __attribute__((aligned(16)));
    __shared__ unsigned short Bsl[2][256 * 64] __attribute__((aligned(16)));

    const int tid  = threadIdx.x;
    const int wid  = tid >> 6;
    const int lane = tid & 63;
    const int wm = wid >> 2, wn = wid & 3;     // 2 x 4 wave grid

    // XCD-aware bijective swizzle: 768 blocks = 8 XCDs x 96
    const int wg = (blockIdx.x & 7) * 96 + (blockIdx.x >> 3);
    const int bx = wg % 12;                    // N tile (3072/256)
    const int by = wg / 12;                    // M tile (16384/256)
    const int m0 = by * 256;
    const int n0 = bx * 256;

    // ---- staging constants: one 8KB load = 64 rows x 128B; thread -> 16B slot.
    // srow = tid>>3, H = (tid>>2)&1, S = tid&3; global k-off applies involution.
    const int srow = tid >> 3;
    const int gk = ((((tid >> 2) & 1) ^ ((tid >> 5) & 1)) << 5)
                 + (((tid & 3) ^ ((tid >> 3) & 3)) << 3);
    const size_t aG = (size_t)(m0 + srow) * K_TOT + gk;
    const size_t bG = (size_t)(n0 + srow) * K_TOT + gk;
    const int ldsW = wid << 9;                 // wave-uniform: rows wid*8 -> wid*8*64

    auto ST = [&](const unsigned short* g, unsigned short* l) {
        __builtin_amdgcn_global_load_lds((const __attribute__((address_space(1))) void*)g,
                                         (__attribute__((address_space(3))) void*)l, 16, 0, 0);
    };
    auto STAGE_A = [&](int t, int h) {         // half h of A K-tile t -> buf t&1
        unsigned short* l = &Asl[t & 1][(h << 13) + ldsW];
        const unsigned short* g = A + aG + ((size_t)(h << 7)) * K_TOT + (size_t)t * 64;
        ST(g, l);
        ST(g + (size_t)64 * K_TOT, l + 4096);
    };
    auto STAGE_B = [&](int t, int h) {
        unsigned short* l = &Bsl[t & 1][(h << 13) + ldsW];
        const unsigned short* g = W + bG + ((size_t)(h << 7)) * K_TOT + (size_t)t * 64;
        ST(g, l);
        ST(g + (size_t)64 * K_TOT, l + 4096);
    };

    // ---- fragment-read constants (inverse of the staging involution)
    const int rl   = lane & 15;
    const int chsw = (((lane >> 4) ^ (rl & 3)) << 3);   // swizzled 16B chunk (elems)
    const int ko0  = ((rl >> 2) & 1) << 5;              // k-half slot holding kk=0
    const int ko1  = ko0 ^ 32;
    const int aro  = (wm * 128 + rl) * 64 + chsw;
    const int bro  = (wn * 64 + rl) * 64 + chsw;

    f32x4 acc[8][4];
#pragma unroll
    for (int i = 0; i < 8; i++)
#pragma unroll
        for (int j = 0; j < 4; j++) acc[i][j] = (f32x4){0.f, 0.f, 0.f, 0.f};

    // one K=64 tile, 4 phases, NO sched_barrier pins (m141 lesson)
    auto TILE = [&](int t, bool stD0, bool stD23, int vm) {
        const unsigned short* Ab = Asl[t & 1];
        const unsigned short* Bb = Bsl[t & 1];
        bf16x8 a0[4][2], a1[4][2], b0[2][2], b1[2][2];
        // ---------- d0: 12 reads + stage A1(t+1) + MFMA (mi0-3 x ni0-1)
#pragma unroll
        for (int mi = 0; mi < 4; mi++) {
            a0[mi][0] = *(const bf16x8*)&Ab[aro + mi * 1024 + ko0];
            a0[mi][1] = *(const bf16x8*)&Ab[aro + mi * 1024 + ko1];
        }
#pragma unroll
        for (int ni = 0; ni < 2; ni++) {
            b0[ni][0] = *(const bf16x8*)&Bb[bro + ni * 1024 + ko0];
            b0[ni][1] = *(const bf16x8*)&Bb[bro + ni * 1024 + ko1];
        }
        if (stD0) STAGE_A(t + 1, 1);
        __builtin_amdgcn_s_barrier();
        asm volatile("s_waitcnt lgkmcnt(0)" ::: "memory");
        __builtin_amdgcn_s_setprio(1);
#pragma unroll
        for (int mi = 0; mi < 4; mi++)
#pragma unroll
            for (int ni = 0; ni < 2; ni++)
#pragma unroll
                for (int kk = 0; kk < 2; kk++)
                    acc[mi][ni] = __builtin_amdgcn_mfma_f32_16x16x32_bf16(a0[mi][kk], b0[ni][kk], acc[mi][ni], 0, 0, 0);
        __builtin_amdgcn_s_setprio(0);
        __builtin_amdgcn_s_barrier();
        // ---------- d1: 4 reads (B ni2-3) + MFMA (mi0-3 x ni2-3)
#pragma unroll
        for (int ni = 0; ni < 2; ni++) {
            b1[ni][0] = *(const bf16x8*)&Bb[bro + (ni + 2) * 1024 + ko0];
            b1[ni][1] = *(const bf16x8*)&Bb[bro + (ni + 2) * 1024 + ko1];
        }
        __builtin_amdgcn_s_barrier();
        asm volatile("s_waitcnt lgkmcnt(0)" ::: "memory");
        __builtin_amdgcn_s_setprio(1);
#pragma unroll
        for (int mi = 0; mi < 4; mi++)
#pragma unroll
            for (int ni = 0; ni < 2; ni++)
#pragma unroll
                for (int kk = 0; kk < 2; kk++)
                    acc[mi][ni + 2] = __builtin_amdgcn_mfma_f32_16x16x32_bf16(a0[mi][kk], b1[ni][kk], acc[mi][ni + 2], 0, 0, 0);
        __builtin_amdgcn_s_setprio(0);
        __builtin_amdgcn_s_barrier();
        // ---------- d2: 8 reads (A mi4-7) + stage B0,B1(t+2) + MFMA (mi4-7 x ni2-3)
#pragma unroll
        for (int mi = 0; mi < 4; mi++) {
            a1[mi][0] = *(const bf16x8*)&Ab[aro + (mi + 4) * 1024 + ko0];
            a1[mi][1] = *(const bf16x8*)&Ab[aro + (mi + 4) * 1024 + ko1];
        }
        if (stD23) { STAGE_B(t + 2, 0); STAGE_B(t + 2, 1); }
        __builtin_amdgcn_s_barrier();
        asm volatile("s_waitcnt lgkmcnt(0)" ::: "memory");
        __builtin_amdgcn_s_setprio(1);
#pragma unroll
        for (int mi = 0; mi < 4; mi++)
#pragma unroll
            for (int ni = 0; ni < 2; ni++)
#pragma unroll
                for (int kk = 0; kk < 2; kk++)
                    acc[mi + 4][ni + 2] = __builtin_amdgcn_mfma_f32_16x16x32_bf16(a1[mi][kk], b1[ni][kk], acc[mi + 4][ni + 2], 0, 0, 0);
        __builtin_amdgcn_s_setprio(0);
        __builtin_amdgcn_s_barrier();
        // ---------- d3: stage A0(t+2) + MFMA (mi4-7 x ni0-1) + boundary vmcnt
        if (stD23) STAGE_A(t + 2, 0);
        __builtin_amdgcn_s_barrier();
        __builtin_amdgcn_s_setprio(1);
#pragma unroll
        for (int mi = 0; mi < 4; mi++)
#pragma unroll
            for (int ni = 0; ni < 2; ni++)
#pragma unroll
                for (int kk = 0; kk < 2; kk++)
                    acc[mi + 4][ni] = __builtin_amdgcn_mfma_f32_16x16x32_bf16(a1[mi][kk], b0[ni][kk], acc[mi + 4][ni], 0, 0, 0);
        __builtin_amdgcn_s_setprio(0);
        if (vm == 6)      asm volatile("s_waitcnt vmcnt(6)" ::: "memory");
        else if (vm == 0) asm volatile("s_waitcnt vmcnt(0)" ::: "memory");
        if (vm >= 0) __builtin_amdgcn_s_barrier();
    };

    // prologue: tile 0 complete (8 loads) + B0(1),B1(1),A0(1) (6 loads);
    // vmcnt(6) retires exactly the oldest 8 = tile 0. A1(1) staged at d0 of tile 0.
    STAGE_A(0, 0); STAGE_A(0, 1); STAGE_B(0, 0); STAGE_B(0, 1);
    STAGE_B(1, 0); STAGE_B(1, 1); STAGE_A(1, 0);
    asm volatile("s_waitcnt vmcnt(6)" ::: "memory");
    __builtin_amdgcn_s_barrier();

    // 16 K-tiles: 14 full + 2 tail. Unroll-2 makes buf index t&1 compile-time.
#pragma unroll 1
    for (int tt = 0; tt < 14; tt += 2) {
        TILE(tt,     true, true, 6);
        TILE(tt + 1, true, true, 6);
    }
    TILE(14, true,  false, 0);   // stages A1(15); drain all before last tile
    TILE(15, false, false, -1);

    // C write + bias (verified fragment->(row,col) convention)
    const int col_l = lane & 15;
    const int quad  = lane >> 4;
#pragma unroll
    for (int mi = 0; mi < 8; mi++) {
#pragma unroll
        for (int ni = 0; ni < 4; ni++) {
            const int gc = n0 + wn * 64 + ni * 16 + col_l;
            const float bias = (gc < H_) ? bq[gc] : (gc < 2 * H_ ? bk[gc - H_] : bv[gc - 2 * H_]);
#pragma unroll
            for (int i = 0; i < 4; i++) {
                const int gr = m0 + wm * 128 + mi * 16 + quad * 4 + i;
                C[(size_t)gr * N_TOT + gc] = f2b(acc[mi][ni][i] + bias);
            }
        }
    }
}

// ------------------------------------------------- global attention (s=0 query)
// grid (B*NH, NCH=16), 256 thr. Phase 1: one key per thread (uint4 K loads).
// Phase 2: vectorized PV — lane = (s-group g, d-octet l); 8 iters of uint4 V
// loads, then 3x shfl_xor reduce across the 8 s-groups.
__global__ __launch_bounds__(256) void gattn_part(const unsigned short* __restrict__ QKV,
                                                  const float* __restrict__ mask,
                                                  float* __restrict__ Pm,
                                                  float* __restrict__ Pl,
                                                  float* __restrict__ Po) {
    const int bh = blockIdx.x;
    const int b = bh >> 4, h = bh & 15;
    const int chunk = blockIdx.y;
    const int tid = threadIdx.x;
    const int w = tid >> 6, lane = tid & 63;

    __shared__ float gq_sh[D_];
    __shared__ float pr[CH];
    __shared__ float red[8];
    __shared__ float osum[4][D_];

    const unsigned short* gqp = QKV + (size_t)(b * S_) * N_TOT + h * D_;
    if (tid < D_) gq_sh[tid] = b2f(gqp[tid]);
    __syncthreads();

    const int s0 = chunk * CH;
    const int s  = s0 + tid;
    const uint4* kp4 = (const uint4*)(QKV + (size_t)(b * S_ + s) * N_TOT + H_ + h * D_);
    float acc = 0.f;
#pragma unroll
    for (int c = 0; c < 8; c++) {
        uint4 r = kp4[c];
        acc += b2f(r.x & 0xffffu) * gq_sh[c * 8 + 0];
        acc += b2f(r.x >> 16)     * gq_sh[c * 8 + 1];
        acc += b2f(r.y & 0xffffu) * gq_sh[c * 8 + 2];
        acc += b2f(r.y >> 16)     * gq_sh[c * 8 + 3];
        acc += b2f(r.z & 0xffffu) * gq_sh[c * 8 + 4];
        acc += b2f(r.z >> 16)     * gq_sh[c * 8 + 5];
        acc += b2f(r.w & 0xffffu) * gq_sh[c * 8 + 6];
        acc += b2f(r.w >> 16)     * gq_sh[c * 8 + 7];
    }
    const float sv = acc * SCALE_ + mask[b * S_ + s];

    float wmax = sv;
#pragma unroll
    for (int m = 32; m >= 1; m >>= 1) wmax = fmaxf(wmax, __shfl_xor(wmax, m, 64));
    if (lane == 0) red[w] = wmax;
    __syncthreads();
    const float bmax = fmaxf(fmaxf(red[0], red[1]), fmaxf(red[2], red[3]));

    const float p = __expf(sv - bmax);
    pr[tid] = p;
    float wsum = p;
#pragma unroll
    for (int m = 32; m >= 1; m >>= 1) wsum += __shfl_xor(wsum, m, 64);
    if (lane == 0) red[4 + w] = wsum;
    __syncthreads();   // publishes pr[] for phase 2
    const float bsum = red[4] + red[5] + red[6] + red[7];

    const int g = lane >> 3;
    const int l = lane & 7;
    float o8[8];
#pragma unroll
    for (int j = 0; j < 8; j++) o8[j] = 0.f;
    const int sbase = s0 + w * 64;
#pragma unroll
    for (int i = 0; i < 8; i++) {
        const int si = sbase + i * 8 + g;
        const uint4 vu = *(const uint4*)(QKV + (size_t)(b * S_ + si) * N_TOT + 2 * H_ + h * D_ + l * 8);
        float vf[8];
        unp8(vu, vf);
        const float pw = pr[w * 64 + i * 8 + g];
#pragma unroll
        for (int j = 0; j < 8; j++) o8[j] += pw * vf[j];
    }
#pragma unroll
    for (int j = 0; j < 8; j++) {
        o8[j] += __shfl_xor(o8[j], 8, 64);
        o8[j] += __shfl_xor(o8[j], 16, 64);
        o8[j] += __shfl_xor(o8[j], 32, 64);
    }
    if (g == 0) {
#pragma unroll
        for (int j = 0; j < 8; j++) osum[w][l * 8 + j] = o8[j];
    }
    __syncthreads();
    if (tid < D_) {
        const float ot = osum[0][tid] + osum[1][tid] + osum[2][tid] + osum[3][tid];
        Po[(size_t)(bh * NCH + chunk) * D_ + tid] = ot;
        if (tid == 0) {
            Pm[bh * NCH + chunk] = bmax;
            Pl[bh * NCH + chunk] = bsum;
        }
    }
}

// ------------------------------------------------- local attention + combine
__global__ __launch_bounds__(256) void lattn(const unsigned short* __restrict__ QKV,
                                             float* __restrict__ ctx,
                                             float* __restrict__ lat,
                                             const float* __restrict__ Pm,
                                             const float* __restrict__ Pl,
                                             const float* __restrict__ Po) {
    const int bh = blockIdx.x;
    const int b = bh >> 4, h = bh & 15;

    if (blockIdx.y == 128) {
        const int d = threadIdx.x;
        if (d < D_) {
            float ms = -1e30f;
#pragma unroll
            for (int c = 0; c < NCH; c++) ms = fmaxf(ms, Pm[bh * NCH + c]);
            float z = 0.f, o = 0.f;
#pragma unroll
            for (int c = 0; c < NCH; c++) {
                const float e = __expf(Pm[bh * NCH + c] - ms);
                z += Pl[bh * NCH + c] * e;
                o += Po[(size_t)(bh * NCH + c) * D_ + d] * e;
            }
            ctx[(size_t)b * S_ * H_ + (size_t)h * D_ + d] = o / z;
        }
        return;
    }

    const int w = threadIdx.x >> 6, lane = threadIdx.x & 63;
    const int g = lane >> 3;     // s-subgroup within wave
    const int l = lane & 7;      // d-octet index
    const int s = 1 + blockIdx.y * 32 + w * 8 + g;
    if (s >= S_) return;         // only the very last 8-lane group; no later barriers

    const size_t rowS = (size_t)(b * S_ + s) * N_TOT + h * D_ + l * 8;
    const size_t row0 = (size_t)(b * S_) * N_TOT + h * D_ + l * 8;

    uint4 qu  = *(const uint4*)(QKV + rowS);
    uint4 ku  = *(const uint4*)(QKV + rowS + H_);
    uint4 k0u = *(const uint4*)(QKV + row0 + H_);
    float qf[8], kf[8], k0f[8];
    unp8(qu, qf); unp8(ku, kf); unp8(k0u, k0f);

    float ps = 0.f, pg = 0.f;
#pragma unroll
    for (int i = 0; i < 8; i++) { ps += qf[i] * kf[i]; pg += qf[i] * k0f[i]; }
#pragma unroll
    for (int m = 1; m < 8; m <<= 1) {   // reduce within the 8-lane d-group
        ps += __shfl_xor(ps, m, 64);
        pg += __shfl_xor(pg, m, 64);
    }
    ps *= SCALE_; pg *= SCALE_;
    const float mx = fmaxf(ps, pg);
    const float e0 = __expf(ps - mx), e1 = __expf(pg - mx);
    const float z = e0 + e1;
    const float p0 = e0 / z, p1 = e1 / z;

    uint4 vu  = *(const uint4*)(QKV + rowS + 2 * H_);
    uint4 v0u = *(const uint4*)(QKV + row0 + 2 * H_);
    float vf[8], v0f[8];
    unp8(vu, vf); unp8(v0u, v0f);

    float* cp = ctx + (size_t)b * (S_ * H_) + (size_t)s * H_ + h * D_ + l * 8;
    float4 o0, o1;
    o0.x = p0 * vf[0] + p1 * v0f[0];
    o0.y = p0 * vf[1] + p1 * v0f[1];
    o0.z = p0 * vf[2] + p1 * v0f[2];
    o0.w = p0 * vf[3] + p1 * v0f[3];
    o1.x = p0 * vf[4] + p1 * v0f[4];
    o1.y = p0 * vf[5] + p1 * v0f[5];
    o1.z = p0 * vf[6] + p1 * v0f[6];
    o1.w = p0 * vf[7] + p1 * v0f[7];
    ((float4*)cp)[0] = o0;
    ((float4*)cp)[1] = o1;

    if (l == 0) {
        float2 lp; lp.x = p0; lp.y = p1;
        ((float2*)(lat + ((size_t)bh * (S_ - 1) + (s - 1)) * 2))[0] = lp;
    }
}

// ---------------------------------------------------------------- launcher
extern "C" void kernel_launch(void* const* d_in, const int* in_sizes, int n_in,
                              void* d_out, int out_size, void* d_ws, size_t ws_size,
                              hipStream_t stream) {
    const float* hs   = (const float*)d_in[0];
    const float* mask = (const float*)d_in[1];
    const float* Wq   = (const float*)d_in[2];
    const float* bq   = (const float*)d_in[3];
    const float* Wk   = (const float*)d_in[4];
    const float* bk   = (const float*)d_in[5];
    const float* Wv   = (const float*)d_in[6];
    const float* bv   = (const float*)d_in[7];

    float* out = (float*)d_out;                       // (B,S,H) fp32
    float* lat = out + (size_t)B_ * S_ * H_;          // (B,NH,S-1,1,2) fp32

    char* ws = (char*)d_ws;
    const size_t offXb  = 0;
    const size_t offWb  = offXb  + (size_t)M_TOT * K_TOT * 2;
    const size_t offQKV = offWb  + (size_t)3 * H_ * H_ * 2;
    const size_t offPm  = offQKV + (size_t)M_TOT * N_TOT * 2;
    const size_t offPl  = offPm  + (size_t)B_ * NH_ * NCH * 4;
    const size_t offPo  = offPl  + (size_t)B_ * NH_ * NCH * 4;

    unsigned short* Xb  = (unsigned short*)(ws + offXb);
    unsigned short* Wb  = (unsigned short*)(ws + offWb);
    unsigned short* QKV = (unsigned short*)(ws + offQKV);
    float* Pm = (float*)(ws + offPm);
    float* Pl = (float*)(ws + offPl);
    float* Po = (float*)(ws + offPo);

    const int total8 = M_TOT * K_TOT / 8 + 3 * H_ * H_ / 8;   // 2490368, /256 exact
    hipLaunchKernelGGL(cvt_all, dim3(total8 / 256), dim3(256), 0, stream,
                       hs, Wq, Wk, Wv, Xb, Wb);
    hipLaunchKernelGGL(gemm_qkv, dim3(12 * 64), dim3(512), 0, stream,
                       Xb, Wb, bq, bk, bv, QKV);
    hipLaunchKernelGGL(gattn_part, dim3(B_ * NH_, NCH), dim3(256), 0, stream, QKV, mask, Pm, Pl, Po);
    hipLaunchKernelGGL(lattn, dim3(B_ * NH_, 129), dim3(256), 0, stream, QKV, out, lat, Pm, Pl, Po);
}